// Round 8
// baseline (305.292 us; speedup 1.0000x reference)
//
#include <hip/hip_runtime.h>
#include <hip/hip_bf16.h>

typedef __attribute__((ext_vector_type(8))) short bf16x8;  // 8 bf16 = 4 VGPRs
typedef __attribute__((ext_vector_type(4))) float f32x4;   // MFMA C/D
typedef __attribute__((ext_vector_type(4))) int   i32x4;

#define BIGC 10000.0f
#define TPW 2          // macro-iterations (64 points per wave each)

__device__ __forceinline__ float fast_exp2(float x) { return __builtin_amdgcn_exp2f(x); }
__device__ __forceinline__ float fast_log2(float x) { return __builtin_amdgcn_logf(x); }
__device__ __forceinline__ float fast_rcp(float x)  { return __builtin_amdgcn_rcpf(x); }

__device__ __forceinline__ float fast_tanh(float x) {
    const float ax = fabsf(x);
    const float e  = fast_exp2(ax * 2.8853900817779268f);   // e^(2|x|)
    const float r  = 1.0f - 2.0f * fast_rcp(e + 1.0f);
    return copysignf(r, x);
}
// softplus(v) + 1e-4 (verified identical numerics since R3).
__device__ __forceinline__ float fast_softplus_eps(float v) {
    const float e = fast_exp2(fabsf(v) * -1.4426950408889634f);  // exp(-|v|)
    const float l = fast_log2(1.0f + e) * 0.6931471805599453f;   // ln(1+e)
    return fmaxf(v, 0.0f) + l + 0.0001f;
}
// Pack two f32 -> two bf16 (RNE) in ONE instruction.
__device__ __forceinline__ unsigned pack2bf(float hi, float lo) {
    unsigned r;
    asm("v_cvt_pk_bf16_f32 %0, %1, %2" : "=v"(r) : "v"(lo), "v"(hi));
    return r;
}

// ============================================================================
// R8 = R7 resubmitted verbatim: R7 died on container acquisition ("MI355X
// container failed twice") — same infra flake as R5, which passed untouched
// when resubmitted as R6. The split thesis is still unmeasured.
//
// Thesis: SPLIT THE CHAIN AT THE KERNEL BOUNDARY. Six rounds proved the
// monolithic kernel is pinned at ~78 us by its serial per-wave chain
// (load-wait -> tanh -> 4 dependent MFMA sub-chains -> LDS round-trip ->
// softplus/interp -> store): every occupancy/ILP/granularity knob was
// neutral; only instruction cuts moved it (R0->R1). Separate KERNELS are
// separate dispatch populations the scheduler can't re-serialize.
//   Kernel A (mlp): phase A+B, d written FEAT-MAJOR to workspace
//     (ws[f*n+p], one float4 store per sub-tile per lane = 10x64B contiguous
//     chunks per instr). No __shared__, no phase C -> short chain ending in
//     a fire-and-forget store.
//   Kernel B (interp): pure elementwise streaming — 10 coalesced d loads
//     (L3-warm from A), x, 10 softplus, interp, store. No MFMA/LDS/
//     cross-lane; the kernel shape that demonstrably runs near-BW here.
// Same-stream launches serialize; kernel-end release fence makes A's writes
// visible to B across XCDs. Numerics bit-identical to R6 (d transits global
// f32 instead of LDS f32). Fallback to proven R6 kernel if ws too small.
// ============================================================================

// ---------------- Kernel A: MLP -> d (feat-major) ----------------
__global__ void __launch_bounds__(64, 6) coupling_mlp(
    const float* __restrict__ x, const float* __restrict__ t_feat,
    const float* __restrict__ W1, const float* __restrict__ b1,
    const float* __restrict__ W2, const float* __restrict__ b2,
    float* __restrict__ dws, int n)
{
    const int lane = threadIdx.x & 63;
    const int m    = lane & 15;
    const int q    = lane >> 4;
    const int m4   = m << 2;

    // ---- constant fragments (built once per WG, resident in VGPRs) ----
    bf16x8 w1f[4];   // GEMM1 A-frags: lane (q,m) elem j = W1row(sigma_z(8q+j))[16a+m]
#pragma unroll
    for (int a = 0; a < 4; ++a) {
        float wv[8];
#pragma unroll
        for (int j = 0; j < 8; ++j) {
            const int k = q * 8 + j;
            const int col = 16 * a + m;
            float v = 0.0f;
            if (k < 16)       v = W1[(k + 2) * 64 + col];
            else if (k == 16) v = W1[0 * 64 + col];
            else if (k == 17) v = W1[1 * 64 + col];
            else if (k == 18) v = b1[col];          // bias folded in
            wv[j] = v;
        }
        i32x4 f = { (int)pack2bf(wv[1], wv[0]), (int)pack2bf(wv[3], wv[2]),
                    (int)pack2bf(wv[5], wv[4]), (int)pack2bf(wv[7], wv[6]) };
        w1f[a] = __builtin_bit_cast(bf16x8, f);
    }
    bf16x8 w2f[2];   // GEMM2 B-frags with sigma row-permutation
#pragma unroll
    for (int fi = 0; fi < 2; ++fi) {
        float wv[8];
#pragma unroll
        for (int j = 0; j < 8; ++j) {
            const int hid = 32 * fi + 16 * (j >> 2) + 4 * q + (j & 3);
            wv[j] = (m < 10) ? W2[hid * 10 + m] : 0.0f;
        }
        i32x4 f = { (int)pack2bf(wv[1], wv[0]), (int)pack2bf(wv[3], wv[2]),
                    (int)pack2bf(wv[5], wv[4]), (int)pack2bf(wv[7], wv[6]) };
        w2f[fi] = __builtin_bit_cast(bf16x8, f);
    }
    const float bias2 = (m < 10) ? b2[m] : 0.0f;

    for (int it = 0; it < TPW; ++it) {
        int pb = (blockIdx.x * TPW + it) * 64;
        pb = max(min(pb, n - 64), 0);   // wave-uniform clamp (n>=64 here);
                                        // tail dups write identical values.

        // x0,x1 for tanh (scalar loads — 12B stride forbids float2 align)
        const float* xp = x + (pb + lane) * 3;
        const float xi0 = xp[0], xi1 = xp[1];

        float4 ta[4], tb[4];
        if (q < 2) {
#pragma unroll
            for (int s = 0; s < 4; ++s) {
                const float4* tr = (const float4*)(t_feat + (pb + 16 * s + m) * 16 + q * 8);
                ta[s] = tr[0];
                tb[s] = tr[1];
            }
        }

        // tanh once per lane on its own point; z-frags pull via bpermute.
        const unsigned pk = pack2bf(fast_tanh(xi1), fast_tanh(xi0));

#pragma unroll
        for (int s = 0; s < 4; ++s) {
            // lane (q=2,m) needs point pb+16s+m -> lives in lane 16s+m
            const int tp = __builtin_amdgcn_ds_bpermute(s * 64 + m4, (int)pk);

            i32x4 zw = { 0, 0, 0, 0 };
            if (q < 2) {
                zw[0] = (int)pack2bf(ta[s].y, ta[s].x);
                zw[1] = (int)pack2bf(ta[s].w, ta[s].z);
                zw[2] = (int)pack2bf(tb[s].y, tb[s].x);
                zw[3] = (int)pack2bf(tb[s].w, tb[s].z);
            } else if (q == 2) {
                zw[0] = tp;                        // [tanh(x1)|tanh(x0)]
                zw[1] = 0x3F80;                    // k=18: bf16(1.0) bias slot
            }
            const bf16x8 zf = __builtin_bit_cast(bf16x8, zw);

            // ---- GEMM1 (transposed): 4 independent MFMAs, bias folded ----
            f32x4 acc[4];
#pragma unroll
            for (int a = 0; a < 4; ++a) {
                f32x4 c = { 0.0f, 0.0f, 0.0f, 0.0f };
                acc[a] = __builtin_amdgcn_mfma_f32_16x16x32_bf16(w1f[a], zf, c, 0, 0, 0);
            }

            // ---- relu + IN-LANE repack to GEMM2 A-frags ----
            float rl[16];
#pragma unroll
            for (int a = 0; a < 4; ++a)
#pragma unroll
                for (int r = 0; r < 4; ++r)
                    rl[4 * a + r] = fmaxf(acc[a][r], 0.0f);
            i32x4 a20 = { (int)pack2bf(rl[1],  rl[0]),  (int)pack2bf(rl[3],  rl[2]),
                          (int)pack2bf(rl[5],  rl[4]),  (int)pack2bf(rl[7],  rl[6]) };
            i32x4 a21 = { (int)pack2bf(rl[9],  rl[8]),  (int)pack2bf(rl[11], rl[10]),
                          (int)pack2bf(rl[13], rl[12]), (int)pack2bf(rl[15], rl[14]) };

            // ---- GEMM2: two INDEPENDENT MFMAs, summed after ----
            f32x4 cb = { bias2, bias2, bias2, bias2 };
            f32x4 cz = { 0.0f, 0.0f, 0.0f, 0.0f };
            f32x4 cd0 = __builtin_amdgcn_mfma_f32_16x16x32_bf16(
                            __builtin_bit_cast(bf16x8, a20), w2f[0], cb, 0, 0, 0);
            f32x4 cd1 = __builtin_amdgcn_mfma_f32_16x16x32_bf16(
                            __builtin_bit_cast(bf16x8, a21), w2f[1], cz, 0, 0, 0);

            // ---- d to workspace, FEAT-MAJOR, one float4 per lane ----
            // regs r=0..3 are consecutive points pb+16s+4q+r  ->  16B store
            // at dws[m*n + pb+16s+4q]; 10 feats x 64B contiguous per instr.
            if (m < 10) {
                f32x4 dsum = { cd0[0] + cd1[0], cd0[1] + cd1[1],
                               cd0[2] + cd1[2], cd0[3] + cd1[3] };
                float4* dst = (float4*)(dws + (size_t)m * n + pb + 16 * s + 4 * q);
                *dst = make_float4(dsum[0], dsum[1], dsum[2], dsum[3]);
            }
        }
    }
}

// ---------------- Kernel B: softplus + interp + store ----------------
__global__ void __launch_bounds__(256, 8) coupling_interp(
    const float* __restrict__ x, const float* __restrict__ mask,
    const float* __restrict__ dws, float* __restrict__ out, int n)
{
    const int p = blockIdx.x * 256 + threadIdx.x;
    if (p >= n) return;

    const float m0 = mask[0], m1 = mask[1];
    const float* xp = x + (size_t)p * 3;
    const float xi0 = xp[0], xi1 = xp[1], xi2 = xp[2];

    // 10 coalesced feat-major loads (stride-1 across lanes), then softplus.
    float dv[10];
#pragma unroll
    for (int f = 0; f < 10; ++f)
        dv[f] = fast_softplus_eps(dws[(size_t)f * n + p]);

    const float dxl2 = dv[0], dxl1 = dv[1], dxr1 = dv[2], dxr2 = dv[3];
    const float dyl2 = dv[4], dyl1 = dv[5], dyr1 = dv[6], dyr2 = dv[7];
    const float kl = dv[8] * 2.0f, kr = dv[9] * 2.0f;

    const float xL1 = -dxl1,        yL1 = -dyl1;
    const float xL2 = -dxl1 - dxl2, yL2 = -dyl1 - dyl2;
    const float xR1 = dxr1,         yR1 = dyr1;
    const float xR2 = dxr1 + dxr2,  yR2 = dyr1 + dyr2;
    const float xR3 = xR2 + BIGC,   yR3 = fmaf(kr, BIGC, yR2);
    const float xL3 = xL2 - BIGC,   yL3 = fmaf(-kl, BIGC, yL2);

    float qx = fminf(fmaxf(xi2, xL3 * 0.99f), xR3 * 0.99f);
    float xl = xL3, xrr = xL2, yl = yL3, yr = yL2;
    if (qx >= xL2) { xl = xL2; xrr = xL1; yl = yL2; yr = yL1; }
    if (qx >= xL1) { xl = xL1; xrr = xR1; yl = yL1; yr = yR1; }
    if (qx >= xR1) { xl = xR1; xrr = xR2; yl = yR1; yr = yR2; }
    if (qx >= xR2) { xl = xR2; xrr = xR3; yl = yR2; yr = yR3; }
    const float slope = (yr - yl) * fast_rcp(xrr - xl);
    const float res = fmaf(slope, qx - xl, yl);

    float* op = out + (size_t)p * 3;
    op[0] = xi0 * m0;
    op[1] = xi1 * m1;
    op[2] = res;
}

// ---------------- Fallback: proven R6 monolithic kernel (78 us) ----------------
__global__ void __launch_bounds__(64, 4) coupling_mfma8(
    const float* __restrict__ x, const float* __restrict__ t_feat,
    const float* __restrict__ mask, const float* __restrict__ W1,
    const float* __restrict__ b1, const float* __restrict__ W2,
    const float* __restrict__ b2, float* __restrict__ out, int n)
{
    __shared__ float lds_d[64][11];

    const int lane = threadIdx.x & 63;
    const int m    = lane & 15;
    const int q    = lane >> 4;
    const int m4   = m << 2;

    bf16x8 w1f[4];
#pragma unroll
    for (int a = 0; a < 4; ++a) {
        float wv[8];
#pragma unroll
        for (int j = 0; j < 8; ++j) {
            const int k = q * 8 + j;
            const int col = 16 * a + m;
            float v = 0.0f;
            if (k < 16)       v = W1[(k + 2) * 64 + col];
            else if (k == 16) v = W1[0 * 64 + col];
            else if (k == 17) v = W1[1 * 64 + col];
            else if (k == 18) v = b1[col];
            wv[j] = v;
        }
        i32x4 f = { (int)pack2bf(wv[1], wv[0]), (int)pack2bf(wv[3], wv[2]),
                    (int)pack2bf(wv[5], wv[4]), (int)pack2bf(wv[7], wv[6]) };
        w1f[a] = __builtin_bit_cast(bf16x8, f);
    }
    bf16x8 w2f[2];
#pragma unroll
    for (int fi = 0; fi < 2; ++fi) {
        float wv[8];
#pragma unroll
        for (int j = 0; j < 8; ++j) {
            const int hid = 32 * fi + 16 * (j >> 2) + 4 * q + (j & 3);
            wv[j] = (m < 10) ? W2[hid * 10 + m] : 0.0f;
        }
        i32x4 f = { (int)pack2bf(wv[1], wv[0]), (int)pack2bf(wv[3], wv[2]),
                    (int)pack2bf(wv[5], wv[4]), (int)pack2bf(wv[7], wv[6]) };
        w2f[fi] = __builtin_bit_cast(bf16x8, f);
    }
    const float bias2 = (m < 10) ? b2[m] : 0.0f;
    const float m0 = mask[0], m1 = mask[1];

    for (int it = 0; it < TPW; ++it) {
        int pb = (blockIdx.x * TPW + it) * 64;
        pb = max(min(pb, n - 64), 0);

        const int pl = pb + lane;
        const float* xp = x + pl * 3;
        const float xi0 = xp[0], xi1 = xp[1], xi2 = xp[2];

        float4 ta[4], tb[4];
        if (q < 2) {
#pragma unroll
            for (int s = 0; s < 4; ++s) {
                const float4* tr = (const float4*)(t_feat + (pb + 16 * s + m) * 16 + q * 8);
                ta[s] = tr[0];
                tb[s] = tr[1];
            }
        }

        const unsigned pk = pack2bf(fast_tanh(xi1), fast_tanh(xi0));

#pragma unroll
        for (int s = 0; s < 4; ++s) {
            const int tp = __builtin_amdgcn_ds_bpermute(s * 64 + m4, (int)pk);

            i32x4 zw = { 0, 0, 0, 0 };
            if (q < 2) {
                zw[0] = (int)pack2bf(ta[s].y, ta[s].x);
                zw[1] = (int)pack2bf(ta[s].w, ta[s].z);
                zw[2] = (int)pack2bf(tb[s].y, tb[s].x);
                zw[3] = (int)pack2bf(tb[s].w, tb[s].z);
            } else if (q == 2) {
                zw[0] = tp;
                zw[1] = 0x3F80;
            }
            const bf16x8 zf = __builtin_bit_cast(bf16x8, zw);

            f32x4 acc[4];
#pragma unroll
            for (int a = 0; a < 4; ++a) {
                f32x4 c = { 0.0f, 0.0f, 0.0f, 0.0f };
                acc[a] = __builtin_amdgcn_mfma_f32_16x16x32_bf16(w1f[a], zf, c, 0, 0, 0);
            }

            float rl[16];
#pragma unroll
            for (int a = 0; a < 4; ++a)
#pragma unroll
                for (int r = 0; r < 4; ++r)
                    rl[4 * a + r] = fmaxf(acc[a][r], 0.0f);
            i32x4 a20 = { (int)pack2bf(rl[1],  rl[0]),  (int)pack2bf(rl[3],  rl[2]),
                          (int)pack2bf(rl[5],  rl[4]),  (int)pack2bf(rl[7],  rl[6]) };
            i32x4 a21 = { (int)pack2bf(rl[9],  rl[8]),  (int)pack2bf(rl[11], rl[10]),
                          (int)pack2bf(rl[13], rl[12]), (int)pack2bf(rl[15], rl[14]) };

            f32x4 cb = { bias2, bias2, bias2, bias2 };
            f32x4 cz = { 0.0f, 0.0f, 0.0f, 0.0f };
            f32x4 cd0 = __builtin_amdgcn_mfma_f32_16x16x32_bf16(
                            __builtin_bit_cast(bf16x8, a20), w2f[0], cb, 0, 0, 0);
            f32x4 cd1 = __builtin_amdgcn_mfma_f32_16x16x32_bf16(
                            __builtin_bit_cast(bf16x8, a21), w2f[1], cz, 0, 0, 0);

#pragma unroll
            for (int r = 0; r < 4; ++r) {
                const float dv = cd0[r] + cd1[r];
                if (m < 10) lds_d[16 * s + 4 * q + r][m] = dv;
            }
        }

        {
            const float* dd = lds_d[lane];
            const float dxl2 = fast_softplus_eps(dd[0]);
            const float dxl1 = fast_softplus_eps(dd[1]);
            const float dxr1 = fast_softplus_eps(dd[2]);
            const float dxr2 = fast_softplus_eps(dd[3]);
            const float dyl2 = fast_softplus_eps(dd[4]);
            const float dyl1 = fast_softplus_eps(dd[5]);
            const float dyr1 = fast_softplus_eps(dd[6]);
            const float dyr2 = fast_softplus_eps(dd[7]);
            const float kl = fast_softplus_eps(dd[8]) * 2.0f;
            const float kr = fast_softplus_eps(dd[9]) * 2.0f;

            const float xL1 = -dxl1,        yL1 = -dyl1;
            const float xL2 = -dxl1 - dxl2, yL2 = -dyl1 - dyl2;
            const float xR1 = dxr1,         yR1 = dyr1;
            const float xR2 = dxr1 + dxr2,  yR2 = dyr1 + dyr2;
            const float xR3 = xR2 + BIGC,   yR3 = fmaf(kr, BIGC, yR2);
            const float xL3 = xL2 - BIGC,   yL3 = fmaf(-kl, BIGC, yL2);

            float qx = fminf(fmaxf(xi2, xL3 * 0.99f), xR3 * 0.99f);
            float xl = xL3, xrr = xL2, yl = yL3, yr = yL2;
            if (qx >= xL2) { xl = xL2; xrr = xL1; yl = yL2; yr = yL1; }
            if (qx >= xL1) { xl = xL1; xrr = xR1; yl = yL1; yr = yR1; }
            if (qx >= xR1) { xl = xR1; xrr = xR2; yl = yR1; yr = yR2; }
            if (qx >= xR2) { xl = xR2; xrr = xR3; yl = yR2; yr = yR3; }
            const float slope = (yr - yl) * fast_rcp(xrr - xl);
            const float res = fmaf(slope, qx - xl, yl);

            float* op = out + pl * 3;
            op[0] = xi0 * m0;
            op[1] = xi1 * m1;
            op[2] = res;
        }
    }
}

extern "C" void kernel_launch(void* const* d_in, const int* in_sizes, int n_in,
                              void* d_out, int out_size, void* d_ws, size_t ws_size,
                              hipStream_t stream) {
    const float* x      = (const float*)d_in[0];
    const float* t_feat = (const float*)d_in[1];
    const float* mask   = (const float*)d_in[2];
    const float* W1     = (const float*)d_in[3];
    const float* b1     = (const float*)d_in[4];
    const float* W2     = (const float*)d_in[5];
    const float* b2     = (const float*)d_in[6];
    float* out = (float*)d_out;

    const int n = in_sizes[0] / 3;                       // 2097152 points
    const size_t need = (size_t)10 * (size_t)n * sizeof(float);   // 80 MB

    if (d_ws != nullptr && ws_size >= need) {
        float* dws = (float*)d_ws;
        const int ppb_a = TPW * 64;                                   // 128
        const int grid_a = (n + ppb_a - 1) / ppb_a;                   // 16384
        coupling_mlp<<<grid_a, 64, 0, stream>>>(x, t_feat, W1, b1, W2, b2, dws, n);
        const int grid_b = (n + 255) / 256;                           // 8192
        coupling_interp<<<grid_b, 256, 0, stream>>>(x, mask, dws, out, n);
    } else {
        const int pts_per_block = TPW * 64;                           // 128
        const int grid = (n + pts_per_block - 1) / pts_per_block;     // 16384
        coupling_mfma8<<<grid, 64, 0, stream>>>(x, t_feat, mask, W1, b1, W2, b2, out, n);
    }
}